// Round 11
// baseline (359.271 us; speedup 1.0000x reference)
//
#include <hip/hip_runtime.h>
#include <math.h>

typedef __attribute__((ext_vector_type(8))) short bf16x8;
typedef __attribute__((ext_vector_type(4))) float f32x4;
typedef unsigned short ushort;
typedef unsigned int uint;

static __device__ __forceinline__ ushort f2bf(float f) {
    unsigned u = __float_as_uint(f);
    u = u + 0x7fff + ((u >> 16) & 1);
    return (ushort)(u >> 16);
}
static __device__ __forceinline__ float bf2f(ushort h) {
    return __uint_as_float(((unsigned)h) << 16);
}

// 16-lane-group sum via DPP (xor1, xor2, half_mirror, mirror) - pure VALU.
template <int CTRL>
static __device__ __forceinline__ float dpp_add(float c) {
    int p = __builtin_amdgcn_update_dpp(0, __float_as_int(c), CTRL, 0xf, 0xf, true);
    return c + __int_as_float(p);
}
static __device__ __forceinline__ float group16_sum(float c) {
    c = dpp_add<0xB1>(c);   // quad_perm xor1
    c = dpp_add<0x4E>(c);   // quad_perm xor2
    c = dpp_add<0x141>(c);  // row_half_mirror (xor 7)
    c = dpp_add<0x140>(c);  // row_mirror (xor 15)
    return c;
}

// ---------------- slotted adjacency: colA[d*64 + slot] = src ----------------

__global__ void k_fill(const int* __restrict__ src, const int* __restrict__ dst,
                       int E, int* __restrict__ counts, int* __restrict__ colA) {
    int i = blockIdx.x * blockDim.x + threadIdx.x;
    if (i < E) {
        int s = src[i], d = dst[i];
        if (s != d) {
            int p = atomicAdd(&counts[d], 1);
            if (p < 64) colA[(size_t)d * 64 + p] = s;
        }
    }
}

// ---------------- weight repack, split bf16 ----------------
// slot j: 0 = W2; 1-4 = Wl1 heads; 5-8 = Wr1 heads; 9-12 = Wl2 k-chunks; 13-16 = Wr2.

__global__ __launch_bounds__(256) void k_repack(
    const float* __restrict__ W2, const float* __restrict__ Wl1,
    const float* __restrict__ Wr1, const float* __restrict__ Wl2,
    const float* __restrict__ Wr2,
    ushort* __restrict__ wfh, ushort* __restrict__ wfl)
{
    int job = blockIdx.y;
    int t = blockIdx.x * 256 + threadIdx.x;
    int ks = t >> 9, n = (t >> 6) & 7, l = t & 63;

    const float* W; int ldw, rowoff, col0;
    if (job == 0)      { W = W2;  ldw = 128; rowoff = 0;              col0 = 0; }
    else if (job < 5)  { W = Wl1; ldw = 512; rowoff = 0;              col0 = (job - 1) * 128; }
    else if (job < 9)  { W = Wr1; ldw = 512; rowoff = 0;              col0 = (job - 5) * 128; }
    else if (job < 13) { W = Wl2; ldw = 128; rowoff = (job - 9) * 128;  col0 = 0; }
    else               { W = Wr2; ldw = 128; rowoff = (job - 13) * 128; col0 = 0; }

    int krow = rowoff + ks * 32 + (l >> 4) * 8;
    int col = col0 + n * 16 + (l & 15);
    size_t dbase = (size_t)job * 16384 + (((size_t)(ks * 8 + n)) * 64 + l) * 8;
#pragma unroll
    for (int j = 0; j < 8; j++) {
        float v = W[(size_t)(krow + j) * ldw + col];
        ushort h = f2bf(v);
        ushort lo = f2bf(v - bf2f(h));
        wfh[dbase + j] = h;
        wfl[dbase + j] = lo;
    }
}

// ---------------- fused MLP: h0 = relu(x@W1+b1)@W2+b2 ----------------

__global__ __launch_bounds__(256) void k_mlp_h0(
    const float* __restrict__ x, const float* __restrict__ W1, const float* __restrict__ b1,
    const ushort* __restrict__ wfh, const ushort* __restrict__ wfl,
    const float* __restrict__ b2,
    ushort* __restrict__ C, int M)
{
    int tid = threadIdx.x;
    int w = tid >> 6, l = tid & 63;
    int m0 = blockIdx.x * 128 + w * 32;
    int lr = l & 15, kg = l >> 4;

    int row0 = m0 + lr, row1 = row0 + 16;
    bool ok0 = row0 < M, ok1 = row1 < M;

    float x0[5], x1[5];
#pragma unroll
    for (int k = 0; k < 5; k++) {
        x0[k] = ok0 ? x[(size_t)row0 * 5 + k] : 0.f;
        x1[k] = ok1 ? x[(size_t)row1 * 5 + k] : 0.f;
    }

    bf16x8 a0[4], a1[4];
#pragma unroll
    for (int ks = 0; ks < 4; ks++) {
#pragma unroll
        for (int j = 0; j < 8; j++) {
            int col = ks * 32 + kg * 8 + j;
            float wc[5];
#pragma unroll
            for (int k = 0; k < 5; k++) wc[k] = W1[k * 128 + col];
            float bb = b1[col];
            float h0v = bb, h1v = bb;
#pragma unroll
            for (int k = 0; k < 5; k++) {
                h0v = fmaf(x0[k], wc[k], h0v);
                h1v = fmaf(x1[k], wc[k], h1v);
            }
            a0[ks][j] = (short)f2bf(fmaxf(h0v, 0.f));
            a1[ks][j] = (short)f2bf(fmaxf(h1v, 0.f));
        }
    }

    f32x4 acc[2][8];
#pragma unroll
    for (int i = 0; i < 2; i++)
#pragma unroll
        for (int j = 0; j < 8; j++) acc[i][j] = (f32x4){0.f, 0.f, 0.f, 0.f};

#pragma unroll
    for (int ks = 0; ks < 4; ks++) {
#pragma unroll
        for (int n = 0; n < 8; n++) {
            size_t bo = (((size_t)(ks * 8 + n)) * 64 + l) * 8;
            bf16x8 bh = *(const bf16x8*)(wfh + bo);
            bf16x8 bl = *(const bf16x8*)(wfl + bo);
            acc[0][n] = __builtin_amdgcn_mfma_f32_16x16x32_bf16(a0[ks], bh, acc[0][n], 0, 0, 0);
            acc[0][n] = __builtin_amdgcn_mfma_f32_16x16x32_bf16(a0[ks], bl, acc[0][n], 0, 0, 0);
            acc[1][n] = __builtin_amdgcn_mfma_f32_16x16x32_bf16(a1[ks], bh, acc[1][n], 0, 0, 0);
            acc[1][n] = __builtin_amdgcn_mfma_f32_16x16x32_bf16(a1[ks], bl, acc[1][n], 0, 0, 0);
        }
    }

#pragma unroll
    for (int mf = 0; mf < 2; mf++) {
#pragma unroll
        for (int r = 0; r < 4; r++) {
            int row = m0 + mf * 16 + kg * 4 + r;
            if (row >= M) continue;
#pragma unroll
            for (int n = 0; n < 8; n++) {
                size_t idx = (size_t)row * 128 + n * 16 + lr;
                C[idx] = f2bf(acc[mf][n][r] + b2[n * 16 + lr]);
            }
        }
    }
}

// ---------------- xl/xr projections, 8 slots per block; dav1 = 0.6*(att . xl) per node/head ----------------

__global__ __launch_bounds__(256) void gemm_xlr1(
    const ushort* __restrict__ A,                                  // h0 bf16 [N][128]
    const ushort* __restrict__ wh, const ushort* __restrict__ wl,  // slot-1 base
    const float* __restrict__ bl1, const float* __restrict__ br1,
    const float* __restrict__ att,                                 // [4][128]
    ushort* __restrict__ out, float* __restrict__ dav1, int M)     // dav1: [N][4]
{
    int tid = threadIdx.x;
    int w = tid >> 6, l = tid & 63;
    int m0 = blockIdx.x * 128 + w * 32;
    int lr = l & 15, kg = l >> 4;

    int row0 = m0 + lr, row1 = row0 + 16;
    bool ok0 = row0 < M, ok1 = row1 < M;
    const bf16x8 zz = {0, 0, 0, 0, 0, 0, 0, 0};

    bf16x8 a0[4], a1[4];
#pragma unroll
    for (int ks = 0; ks < 4; ks++) {
        int koff = ks * 32 + kg * 8;
        a0[ks] = ok0 ? *(const bf16x8*)(A + (size_t)row0 * 128 + koff) : zz;
        a1[ks] = ok1 ? *(const bf16x8*)(A + (size_t)row1 * 128 + koff) : zz;
    }

    for (int t = 0; t < 8; t++) {
        const ushort* bh_base = wh + (size_t)t * 16384;
        const ushort* bl_base = wl + (size_t)t * 16384;

        f32x4 acc[2][8];
#pragma unroll
        for (int i = 0; i < 2; i++)
#pragma unroll
            for (int j = 0; j < 8; j++) acc[i][j] = (f32x4){0.f, 0.f, 0.f, 0.f};

#pragma unroll
        for (int ks = 0; ks < 4; ks++) {
#pragma unroll
            for (int n = 0; n < 8; n++) {
                size_t bo = (((size_t)(ks * 8 + n)) * 64 + l) * 8;
                bf16x8 bh = *(const bf16x8*)(bh_base + bo);
                bf16x8 bl = *(const bf16x8*)(bl_base + bo);
                acc[0][n] = __builtin_amdgcn_mfma_f32_16x16x32_bf16(a0[ks], bh, acc[0][n], 0, 0, 0);
                acc[0][n] = __builtin_amdgcn_mfma_f32_16x16x32_bf16(a0[ks], bl, acc[0][n], 0, 0, 0);
                acc[1][n] = __builtin_amdgcn_mfma_f32_16x16x32_bf16(a1[ks], bh, acc[1][n], 0, 0, 0);
                acc[1][n] = __builtin_amdgcn_mfma_f32_16x16x32_bf16(a1[ks], bl, acc[1][n], 0, 0, 0);
            }
        }

        float bcol[8];
#pragma unroll
        for (int n = 0; n < 8; n++)
            bcol[n] = (t < 4) ? bl1[t * 128 + n * 16 + lr] : br1[(t - 4) * 128 + n * 16 + lr];

        if (t < 4) {
            // xl slot: write outputs + per-row logit dot (0.6 * att . val)
            float at6[8];
#pragma unroll
            for (int n = 0; n < 8; n++) at6[n] = 0.6f * att[t * 128 + n * 16 + lr];
#pragma unroll
            for (int mf = 0; mf < 2; mf++) {
#pragma unroll
                for (int r = 0; r < 4; r++) {
                    int row = m0 + mf * 16 + kg * 4 + r;
                    if (row >= M) continue;
                    float partial = 0.f;
#pragma unroll
                    for (int n = 0; n < 8; n++) {
                        float v = acc[mf][n][r] + bcol[n];
                        partial = fmaf(at6[n], v, partial);
                        out[(size_t)row * 1024 + t * 128 + n * 16 + lr] = f2bf(v);
                    }
                    float red = group16_sum(partial);
                    if (lr == 0) dav1[(size_t)row * 4 + t] = red;
                }
            }
        } else {
#pragma unroll
            for (int mf = 0; mf < 2; mf++) {
#pragma unroll
                for (int r = 0; r < 4; r++) {
                    int row = m0 + mf * 16 + kg * 4 + r;
                    if (row >= M) continue;
#pragma unroll
                    for (int n = 0; n < 8; n++)
                        out[(size_t)row * 1024 + t * 128 + n * 16 + lr] = f2bf(acc[mf][n][r] + bcol[n]);
                }
            }
        }
    }
}

// ---------------- xl2/xr2: K=512, both outputs; dav2 = 0.6*(att2 . xl2) per node ----------------

__global__ __launch_bounds__(256) void gemm_xlr2(
    const ushort* __restrict__ A,                                   // h1 bf16 [N][512]
    const ushort* __restrict__ wfh, const ushort* __restrict__ wfl,
    const float* __restrict__ bl2, const float* __restrict__ br2,
    const float* __restrict__ att,                                  // [128]
    ushort* __restrict__ xl2, ushort* __restrict__ xr2,
    float* __restrict__ dav2, int M)
{
    int tid = threadIdx.x;
    int w = tid >> 6, l = tid & 63;
    int m0 = blockIdx.x * 64 + w * 16;
    int lr = l & 15, kg = l >> 4;

    int row0 = m0 + lr;
    bool ok0 = row0 < M;
    const bf16x8 zz = {0, 0, 0, 0, 0, 0, 0, 0};

    f32x4 acc[2][8];
#pragma unroll
    for (int i = 0; i < 2; i++)
#pragma unroll
        for (int j = 0; j < 8; j++) acc[i][j] = (f32x4){0.f, 0.f, 0.f, 0.f};

    for (int kc = 0; kc < 4; kc++) {
        bf16x8 ah[4];
#pragma unroll
        for (int ks = 0; ks < 4; ks++)
            ah[ks] = ok0 ? *(const bf16x8*)(A + (size_t)row0 * 512 + kc * 128 + ks * 32 + kg * 8) : zz;

#pragma unroll
        for (int t = 0; t < 2; t++) {
            const ushort* bh_base = wfh + (size_t)(9 + t * 4 + kc) * 16384;
            const ushort* bl_base = wfl + (size_t)(9 + t * 4 + kc) * 16384;
#pragma unroll
            for (int ks = 0; ks < 4; ks++) {
#pragma unroll
                for (int n = 0; n < 8; n++) {
                    size_t bo = (((size_t)(ks * 8 + n)) * 64 + l) * 8;
                    bf16x8 bh = *(const bf16x8*)(bh_base + bo);
                    bf16x8 bl = *(const bf16x8*)(bl_base + bo);
                    acc[t][n] = __builtin_amdgcn_mfma_f32_16x16x32_bf16(ah[ks], bh, acc[t][n], 0, 0, 0);
                    acc[t][n] = __builtin_amdgcn_mfma_f32_16x16x32_bf16(ah[ks], bl, acc[t][n], 0, 0, 0);
                }
            }
        }
    }

    float at6[8];
#pragma unroll
    for (int n = 0; n < 8; n++) at6[n] = 0.6f * att[n * 16 + lr];

#pragma unroll
    for (int r = 0; r < 4; r++) {
        int row = m0 + kg * 4 + r;
        if (row >= M) continue;
        float partial = 0.f;
#pragma unroll
        for (int n = 0; n < 8; n++) {
            int col = n * 16 + lr;
            float vl = acc[0][n][r] + bl2[col];
            partial = fmaf(at6[n], vl, partial);
            xl2[(size_t)row * 128 + col] = f2bf(vl);
            xr2[(size_t)row * 128 + col] = f2bf(acc[1][n][r] + br2[col]);
        }
        float red = group16_sum(partial);
        if (lr == 0) dav2[row] = red;
    }
}

// ---------------- GAT1 edge kernel: split logit (abs part per edge + precomputed dav) ----------------

__global__ __launch_bounds__(256) void gat_edge4(
    const ushort* __restrict__ xlr,   // [N][8][128] bf16
    const float* __restrict__ att,    // [4][128]
    const float* __restrict__ bias,   // [512]
    const int* __restrict__ counts, const int* __restrict__ colA,
    const float* __restrict__ dav1,   // [N][4] = 0.6*(att.xl)
    ushort* __restrict__ h1, int N)
{
    int n = blockIdx.x;
    int h = threadIdx.x >> 6, l = threadIdx.x & 63;
    int g = l >> 4, q = l & 15;

    const ushort* xlbase = xlr + h * 128 + q * 8;

    bf16x8 xrv = *(const bf16x8*)(xlr + (size_t)n * 1024 + (4 + h) * 128 + q * 8);
    float4 ata = *(const float4*)(att + h * 128 + q * 8);
    float4 atb = *(const float4*)(att + h * 128 + q * 8 + 4);
    float xr[8], at4[8] = {0.4f*ata.x, 0.4f*ata.y, 0.4f*ata.z, 0.4f*ata.w,
                           0.4f*atb.x, 0.4f*atb.y, 0.4f*atb.z, 0.4f*atb.w};
#pragma unroll
    for (int j = 0; j < 8; j++) xr[j] = bf2f((ushort)xrv[j]);

    // abs-part of logit: group16_sum(sum 0.4*att*|v+xr|); vv = unpacked v
    auto absdot = [&](bf16x8 v8, float* vv) -> float {
        float c = 0.f;
#pragma unroll
        for (int j = 0; j < 8; j++) {
            vv[j] = bf2f((ushort)v8[j]);
            float t = vv[j] + xr[j];
            c = fmaf(at4[j], fabsf(t), c);
        }
        return group16_sum(c);
    };

    float selfv[8];
    bf16x8 vself = *(const bf16x8*)(xlbase + (size_t)n * 1024);
    float cs = absdot(vself, selfv) + dav1[(size_t)n * 4 + h];

    int cnt = min(counts[n], 64);
    const int* col = colA + (size_t)n * 64;

    float s = 0.f, o[8];
#pragma unroll
    for (int j = 0; j < 8; j++) o[j] = 0.f;

    auto edge = [&](bf16x8 v8, float dv) {
        float vv[8];
        float c = absdot(v8, vv) + dv;
        float p = __expf(fminf(c - cs, 80.f));
        s += p;
#pragma unroll
        for (int j = 0; j < 8; j++) o[j] = fmaf(p, vv[j], o[j]);
    };

    for (int base = g; base < cnt; base += 16) {
        int x0 = col[base];
        int x1 = (base + 4  < cnt) ? col[base + 4]  : -1;
        int x2 = (base + 8  < cnt) ? col[base + 8]  : -1;
        int x3 = (base + 12 < cnt) ? col[base + 12] : -1;
        int y1 = (x1 >= 0) ? x1 : n;
        int y2 = (x2 >= 0) ? x2 : n;
        int y3 = (x3 >= 0) ? x3 : n;
        bf16x8 v0 = *(const bf16x8*)(xlbase + (size_t)x0 * 1024);
        bf16x8 v1 = *(const bf16x8*)(xlbase + (size_t)y1 * 1024);
        bf16x8 v2 = *(const bf16x8*)(xlbase + (size_t)y2 * 1024);
        bf16x8 v3 = *(const bf16x8*)(xlbase + (size_t)y3 * 1024);
        float d0 = dav1[(size_t)x0 * 4 + h];
        float d1 = dav1[(size_t)y1 * 4 + h];
        float d2 = dav1[(size_t)y2 * 4 + h];
        float d3 = dav1[(size_t)y3 * 4 + h];
        edge(v0, d0);
        if (x1 >= 0) edge(v1, d1);
        if (x2 >= 0) edge(v2, d2);
        if (x3 >= 0) edge(v3, d3);
    }

#pragma unroll
    for (int off = 16; off <= 32; off <<= 1) {
        s += __shfl_xor(s, off);
#pragma unroll
        for (int j = 0; j < 8; j++) o[j] += __shfl_xor(o[j], off);
    }

    // implicit self-loop: p = 1
    s += 1.f;
#pragma unroll
    for (int j = 0; j < 8; j++) o[j] += selfv[j];

    if (g == 0) {
        float inv = 1.f / (s + 1e-16f);
        float4 ba = *(const float4*)(bias + h * 128 + q * 8);
        float4 bb = *(const float4*)(bias + h * 128 + q * 8 + 4);
        float bs[8] = {ba.x, ba.y, ba.z, ba.w, bb.x, bb.y, bb.z, bb.w};
        bf16x8 pk;
#pragma unroll
        for (int j = 0; j < 8; j++)
            pk[j] = (short)f2bf(fmaxf(o[j] * inv + bs[j], 0.f));
        *(bf16x8*)(h1 + (size_t)n * 512 + h * 128 + q * 8) = pk;
    }
}

// ---------------- GAT2 edge kernel ----------------

__global__ __launch_bounds__(256) void gat_edge1(
    const ushort* __restrict__ xl, const ushort* __restrict__ xr,
    const float* __restrict__ att, const float* __restrict__ bias,
    const int* __restrict__ counts, const int* __restrict__ colA,
    const float* __restrict__ dav2,   // [N] = 0.6*(att.xl2)
    float* __restrict__ out, int N)
{
    int n = blockIdx.x * 4 + (threadIdx.x >> 6);
    if (n >= N) return;
    int l = threadIdx.x & 63;
    int g = l >> 4, q = l & 15;

    const ushort* xlbase = xl + q * 8;

    bf16x8 xrv = *(const bf16x8*)(xr + (size_t)n * 128 + q * 8);
    float4 ata = *(const float4*)(att + q * 8);
    float4 atb = *(const float4*)(att + q * 8 + 4);
    float xrr[8], at4[8] = {0.4f*ata.x, 0.4f*ata.y, 0.4f*ata.z, 0.4f*ata.w,
                            0.4f*atb.x, 0.4f*atb.y, 0.4f*atb.z, 0.4f*atb.w};
#pragma unroll
    for (int j = 0; j < 8; j++) xrr[j] = bf2f((ushort)xrv[j]);

    auto absdot = [&](bf16x8 v8, float* vv) -> float {
        float c = 0.f;
#pragma unroll
        for (int j = 0; j < 8; j++) {
            vv[j] = bf2f((ushort)v8[j]);
            float t = vv[j] + xrr[j];
            c = fmaf(at4[j], fabsf(t), c);
        }
        return group16_sum(c);
    };

    float selfv[8];
    bf16x8 vself = *(const bf16x8*)(xlbase + (size_t)n * 128);
    float cs = absdot(vself, selfv) + dav2[n];

    int cnt = min(counts[n], 64);
    const int* col = colA + (size_t)n * 64;

    float s = 0.f, o[8];
#pragma unroll
    for (int j = 0; j < 8; j++) o[j] = 0.f;

    auto edge = [&](bf16x8 v8, float dv) {
        float vv[8];
        float c = absdot(v8, vv) + dv;
        float p = __expf(fminf(c - cs, 80.f));
        s += p;
#pragma unroll
        for (int j = 0; j < 8; j++) o[j] = fmaf(p, vv[j], o[j]);
    };

    for (int base = g; base < cnt; base += 16) {
        int x0 = col[base];
        int x1 = (base + 4  < cnt) ? col[base + 4]  : -1;
        int x2 = (base + 8  < cnt) ? col[base + 8]  : -1;
        int x3 = (base + 12 < cnt) ? col[base + 12] : -1;
        int y1 = (x1 >= 0) ? x1 : n;
        int y2 = (x2 >= 0) ? x2 : n;
        int y3 = (x3 >= 0) ? x3 : n;
        bf16x8 v0 = *(const bf16x8*)(xlbase + (size_t)x0 * 128);
        bf16x8 v1 = *(const bf16x8*)(xlbase + (size_t)y1 * 128);
        bf16x8 v2 = *(const bf16x8*)(xlbase + (size_t)y2 * 128);
        bf16x8 v3 = *(const bf16x8*)(xlbase + (size_t)y3 * 128);
        float d0 = dav2[x0];
        float d1 = dav2[y1];
        float d2 = dav2[y2];
        float d3 = dav2[y3];
        edge(v0, d0);
        if (x1 >= 0) edge(v1, d1);
        if (x2 >= 0) edge(v2, d2);
        if (x3 >= 0) edge(v3, d3);
    }

#pragma unroll
    for (int off = 16; off <= 32; off <<= 1) {
        s += __shfl_xor(s, off);
#pragma unroll
        for (int j = 0; j < 8; j++) o[j] += __shfl_xor(o[j], off);
    }

    s += 1.f;
#pragma unroll
    for (int j = 0; j < 8; j++) o[j] += selfv[j];

    if (g == 0) {
        float inv = 1.f / (s + 1e-16f);
        float4 ba = *(const float4*)(bias + q * 8);
        float4 bb = *(const float4*)(bias + q * 8 + 4);
        float4 r0, r1;
        r0.x = o[0] * inv + ba.x;  r0.y = o[1] * inv + ba.y;
        r0.z = o[2] * inv + ba.z;  r0.w = o[3] * inv + ba.w;
        r1.x = o[4] * inv + bb.x;  r1.y = o[5] * inv + bb.y;
        r1.z = o[6] * inv + bb.z;  r1.w = o[7] * inv + bb.w;
        *(float4*)(out + (size_t)n * 128 + q * 8)     = r0;
        *(float4*)(out + (size_t)n * 128 + q * 8 + 4) = r1;
    }
}

// ---------------- launch ----------------

extern "C" void kernel_launch(void* const* d_in, const int* in_sizes, int n_in,
                              void* d_out, int out_size, void* d_ws, size_t ws_size,
                              hipStream_t stream) {
    const float* x    = (const float*)d_in[0];
    const int* ei     = (const int*)d_in[1];
    const float* W1   = (const float*)d_in[2];
    const float* b1   = (const float*)d_in[3];
    const float* W2   = (const float*)d_in[4];
    const float* b2   = (const float*)d_in[5];
    const float* Wl1  = (const float*)d_in[6];
    const float* bl1  = (const float*)d_in[7];
    const float* Wr1  = (const float*)d_in[8];
    const float* br1  = (const float*)d_in[9];
    const float* att1 = (const float*)d_in[10];
    const float* bias1= (const float*)d_in[11];
    const float* Wl2  = (const float*)d_in[12];
    const float* bl2  = (const float*)d_in[13];
    const float* Wr2  = (const float*)d_in[14];
    const float* br2  = (const float*)d_in[15];
    const float* att2 = (const float*)d_in[16];
    const float* bias2= (const float*)d_in[17];

    int E = in_sizes[1] / 2;
    int N = in_sizes[0] / 5;
    const int* srcE = ei;
    const int* dstE = ei + E;

    float* dout = (float*)d_out;

    // workspace layout (~194 MB)
    ushort* xlr1 = (ushort*)d_ws;                  // N*1024
    ushort* h1   = xlr1 + (size_t)N * 1024;        // N*512
    ushort* h0   = h1 + (size_t)N * 512;           // N*128
    ushort* xr2  = h0 + (size_t)N * 128;           // N*128
    ushort* wfh  = xr2 + (size_t)N * 128;          // 17*16384
    ushort* wfl  = wfh + 17 * 16384;
    int* counts = (int*)(wfl + 17 * 16384);        // N
    int* colA   = counts + N;                      // N*64
    float* dav1 = (float*)(colA + (size_t)N * 64); // N*4
    float* dav2 = dav1 + (size_t)N * 4;            // N

    ushort* xl2 = h0;   // h0 dead after gemm_xlr1

    // ---- adjacency ----
    hipMemsetAsync(counts, 0, (size_t)N * sizeof(int), stream);
    k_fill<<<(E + 255) / 256, 256, 0, stream>>>(srcE, dstE, E, counts, colA);

    // ---- repack ----
    {
        dim3 g(8, 17);
        k_repack<<<g, 256, 0, stream>>>(W2, Wl1, Wr1, Wl2, Wr2, wfh, wfl);
    }

    int mb128 = (N + 127) / 128;
    int mb64  = (N + 63) / 64;

    // ---- fused MLP -> h0 ----
    k_mlp_h0<<<mb128, 256, 0, stream>>>(x, W1, b1, wfh, wfl, b2, h0, N);

    // ---- GAT1 ----
    gemm_xlr1<<<mb128, 256, 0, stream>>>(h0, wfh + 16384, wfl + 16384, bl1, br1, att1,
                                         xlr1, dav1, N);
    gat_edge4<<<N, 256, 0, stream>>>(xlr1, att1, bias1, counts, colA, dav1, h1, N);

    // ---- GAT2 ----
    gemm_xlr2<<<mb64, 256, 0, stream>>>(h1, wfh, wfl, bl2, br2, att2, xl2, xr2, dav2, N);
    gat_edge1<<<(N + 3) / 4, 256, 0, stream>>>(xl2, xr2, att2, bias2, counts, colA, dav2, dout, N);
}

// Round 12
// 339.418 us; speedup vs baseline: 1.0585x; 1.0585x over previous
//
#include <hip/hip_runtime.h>
#include <math.h>

typedef __attribute__((ext_vector_type(8))) short bf16x8;
typedef __attribute__((ext_vector_type(4))) float f32x4;
typedef unsigned short ushort;
typedef unsigned int uint;

static __device__ __forceinline__ ushort f2bf(float f) {
    unsigned u = __float_as_uint(f);
    u = u + 0x7fff + ((u >> 16) & 1);
    return (ushort)(u >> 16);
}
static __device__ __forceinline__ float bf2f(ushort h) {
    return __uint_as_float(((unsigned)h) << 16);
}

// 16-lane-group sum via DPP (xor1, xor2, half_mirror, mirror) - pure VALU.
template <int CTRL>
static __device__ __forceinline__ float dpp_add(float c) {
    int p = __builtin_amdgcn_update_dpp(0, __float_as_int(c), CTRL, 0xf, 0xf, true);
    return c + __int_as_float(p);
}
static __device__ __forceinline__ float group16_sum(float c) {
    c = dpp_add<0xB1>(c);   // quad_perm xor1
    c = dpp_add<0x4E>(c);   // quad_perm xor2
    c = dpp_add<0x141>(c);  // row_half_mirror (xor 7)
    c = dpp_add<0x140>(c);  // row_mirror (xor 15)
    return c;
}

// ---------------- slotted adjacency: colA[d*64 + slot] = src ----------------

__global__ void k_fill(const int* __restrict__ src, const int* __restrict__ dst,
                       int E, int* __restrict__ counts, int* __restrict__ colA) {
    int i = blockIdx.x * blockDim.x + threadIdx.x;
    if (i < E) {
        int s = src[i], d = dst[i];
        if (s != d) {
            int p = atomicAdd(&counts[d], 1);
            if (p < 64) colA[(size_t)d * 64 + p] = s;
        }
    }
}

// ---------------- weight repack, split bf16 ----------------
// slot j: 0 = W2; 1-4 = Wl1 heads; 5-8 = Wr1 heads; 9-12 = Wl2 k-chunks; 13-16 = Wr2.

__global__ __launch_bounds__(256) void k_repack(
    const float* __restrict__ W2, const float* __restrict__ Wl1,
    const float* __restrict__ Wr1, const float* __restrict__ Wl2,
    const float* __restrict__ Wr2,
    ushort* __restrict__ wfh, ushort* __restrict__ wfl)
{
    int job = blockIdx.y;
    int t = blockIdx.x * 256 + threadIdx.x;
    int ks = t >> 9, n = (t >> 6) & 7, l = t & 63;

    const float* W; int ldw, rowoff, col0;
    if (job == 0)      { W = W2;  ldw = 128; rowoff = 0;              col0 = 0; }
    else if (job < 5)  { W = Wl1; ldw = 512; rowoff = 0;              col0 = (job - 1) * 128; }
    else if (job < 9)  { W = Wr1; ldw = 512; rowoff = 0;              col0 = (job - 5) * 128; }
    else if (job < 13) { W = Wl2; ldw = 128; rowoff = (job - 9) * 128;  col0 = 0; }
    else               { W = Wr2; ldw = 128; rowoff = (job - 13) * 128; col0 = 0; }

    int krow = rowoff + ks * 32 + (l >> 4) * 8;
    int col = col0 + n * 16 + (l & 15);
    size_t dbase = (size_t)job * 16384 + (((size_t)(ks * 8 + n)) * 64 + l) * 8;
#pragma unroll
    for (int j = 0; j < 8; j++) {
        float v = W[(size_t)(krow + j) * ldw + col];
        ushort h = f2bf(v);
        ushort lo = f2bf(v - bf2f(h));
        wfh[dbase + j] = h;
        wfl[dbase + j] = lo;
    }
}

// ---------------- fused MLP: h0 = relu(x@W1+b1)@W2+b2 ----------------

__global__ __launch_bounds__(256) void k_mlp_h0(
    const float* __restrict__ x, const float* __restrict__ W1, const float* __restrict__ b1,
    const ushort* __restrict__ wfh, const ushort* __restrict__ wfl,
    const float* __restrict__ b2,
    ushort* __restrict__ C, int M)
{
    int tid = threadIdx.x;
    int w = tid >> 6, l = tid & 63;
    int m0 = blockIdx.x * 128 + w * 32;
    int lr = l & 15, kg = l >> 4;

    int row0 = m0 + lr, row1 = row0 + 16;
    bool ok0 = row0 < M, ok1 = row1 < M;

    float x0[5], x1[5];
#pragma unroll
    for (int k = 0; k < 5; k++) {
        x0[k] = ok0 ? x[(size_t)row0 * 5 + k] : 0.f;
        x1[k] = ok1 ? x[(size_t)row1 * 5 + k] : 0.f;
    }

    bf16x8 a0[4], a1[4];
#pragma unroll
    for (int ks = 0; ks < 4; ks++) {
#pragma unroll
        for (int j = 0; j < 8; j++) {
            int col = ks * 32 + kg * 8 + j;
            float wc[5];
#pragma unroll
            for (int k = 0; k < 5; k++) wc[k] = W1[k * 128 + col];
            float bb = b1[col];
            float h0v = bb, h1v = bb;
#pragma unroll
            for (int k = 0; k < 5; k++) {
                h0v = fmaf(x0[k], wc[k], h0v);
                h1v = fmaf(x1[k], wc[k], h1v);
            }
            a0[ks][j] = (short)f2bf(fmaxf(h0v, 0.f));
            a1[ks][j] = (short)f2bf(fmaxf(h1v, 0.f));
        }
    }

    f32x4 acc[2][8];
#pragma unroll
    for (int i = 0; i < 2; i++)
#pragma unroll
        for (int j = 0; j < 8; j++) acc[i][j] = (f32x4){0.f, 0.f, 0.f, 0.f};

#pragma unroll
    for (int ks = 0; ks < 4; ks++) {
#pragma unroll
        for (int n = 0; n < 8; n++) {
            size_t bo = (((size_t)(ks * 8 + n)) * 64 + l) * 8;
            bf16x8 bh = *(const bf16x8*)(wfh + bo);
            bf16x8 bl = *(const bf16x8*)(wfl + bo);
            acc[0][n] = __builtin_amdgcn_mfma_f32_16x16x32_bf16(a0[ks], bh, acc[0][n], 0, 0, 0);
            acc[0][n] = __builtin_amdgcn_mfma_f32_16x16x32_bf16(a0[ks], bl, acc[0][n], 0, 0, 0);
            acc[1][n] = __builtin_amdgcn_mfma_f32_16x16x32_bf16(a1[ks], bh, acc[1][n], 0, 0, 0);
            acc[1][n] = __builtin_amdgcn_mfma_f32_16x16x32_bf16(a1[ks], bl, acc[1][n], 0, 0, 0);
        }
    }

#pragma unroll
    for (int mf = 0; mf < 2; mf++) {
#pragma unroll
        for (int r = 0; r < 4; r++) {
            int row = m0 + mf * 16 + kg * 4 + r;
            if (row >= M) continue;
#pragma unroll
            for (int n = 0; n < 8; n++) {
                size_t idx = (size_t)row * 128 + n * 16 + lr;
                C[idx] = f2bf(acc[mf][n][r] + b2[n * 16 + lr]);
            }
        }
    }
}

// ---------------- xl/xr head projections: 8 slots per block (A-reuse), B from global ----------------

__global__ __launch_bounds__(256) void gemm_xlr1(
    const ushort* __restrict__ A,                                  // h0 bf16 [N][128]
    const ushort* __restrict__ wh, const ushort* __restrict__ wl,  // slot-1 base
    const float* __restrict__ bl1, const float* __restrict__ br1,
    ushort* __restrict__ out, int M)
{
    int tid = threadIdx.x;
    int w = tid >> 6, l = tid & 63;
    int m0 = blockIdx.x * 128 + w * 32;
    int lr = l & 15, kg = l >> 4;

    int row0 = m0 + lr, row1 = row0 + 16;
    bool ok0 = row0 < M, ok1 = row1 < M;
    const bf16x8 zz = {0, 0, 0, 0, 0, 0, 0, 0};

    bf16x8 a0[4], a1[4];
#pragma unroll
    for (int ks = 0; ks < 4; ks++) {
        int koff = ks * 32 + kg * 8;
        a0[ks] = ok0 ? *(const bf16x8*)(A + (size_t)row0 * 128 + koff) : zz;
        a1[ks] = ok1 ? *(const bf16x8*)(A + (size_t)row1 * 128 + koff) : zz;
    }

    for (int t = 0; t < 8; t++) {
        const ushort* bh_base = wh + (size_t)t * 16384;
        const ushort* bl_base = wl + (size_t)t * 16384;

        f32x4 acc[2][8];
#pragma unroll
        for (int i = 0; i < 2; i++)
#pragma unroll
            for (int j = 0; j < 8; j++) acc[i][j] = (f32x4){0.f, 0.f, 0.f, 0.f};

#pragma unroll
        for (int ks = 0; ks < 4; ks++) {
#pragma unroll
            for (int n = 0; n < 8; n++) {
                size_t bo = (((size_t)(ks * 8 + n)) * 64 + l) * 8;
                bf16x8 bh = *(const bf16x8*)(bh_base + bo);
                bf16x8 bl = *(const bf16x8*)(bl_base + bo);
                acc[0][n] = __builtin_amdgcn_mfma_f32_16x16x32_bf16(a0[ks], bh, acc[0][n], 0, 0, 0);
                acc[0][n] = __builtin_amdgcn_mfma_f32_16x16x32_bf16(a0[ks], bl, acc[0][n], 0, 0, 0);
                acc[1][n] = __builtin_amdgcn_mfma_f32_16x16x32_bf16(a1[ks], bh, acc[1][n], 0, 0, 0);
                acc[1][n] = __builtin_amdgcn_mfma_f32_16x16x32_bf16(a1[ks], bl, acc[1][n], 0, 0, 0);
            }
        }

        float bcol[8];
#pragma unroll
        for (int n = 0; n < 8; n++)
            bcol[n] = (t < 4) ? bl1[t * 128 + n * 16 + lr] : br1[(t - 4) * 128 + n * 16 + lr];

#pragma unroll
        for (int mf = 0; mf < 2; mf++) {
#pragma unroll
            for (int r = 0; r < 4; r++) {
                int row = m0 + mf * 16 + kg * 4 + r;
                if (row >= M) continue;
#pragma unroll
                for (int n = 0; n < 8; n++)
                    out[(size_t)row * 1024 + t * 128 + n * 16 + lr] = f2bf(acc[mf][n][r] + bcol[n]);
            }
        }
    }
}

// ---------------- xl2/xr2: both outputs per block (A-reuse), K=512, B from global ----------------

__global__ __launch_bounds__(256) void gemm_xlr2(
    const ushort* __restrict__ A,                                   // h1 bf16 [N][512]
    const ushort* __restrict__ wfh, const ushort* __restrict__ wfl, // full table (slots 9..16)
    const float* __restrict__ bl2, const float* __restrict__ br2,
    ushort* __restrict__ xl2, ushort* __restrict__ xr2, int M)
{
    int tid = threadIdx.x;
    int w = tid >> 6, l = tid & 63;
    int m0 = blockIdx.x * 64 + w * 16;
    int lr = l & 15, kg = l >> 4;

    int row0 = m0 + lr;
    bool ok0 = row0 < M;
    const bf16x8 zz = {0, 0, 0, 0, 0, 0, 0, 0};

    f32x4 acc[2][8];
#pragma unroll
    for (int i = 0; i < 2; i++)
#pragma unroll
        for (int j = 0; j < 8; j++) acc[i][j] = (f32x4){0.f, 0.f, 0.f, 0.f};

    for (int kc = 0; kc < 4; kc++) {
        bf16x8 ah[4];
#pragma unroll
        for (int ks = 0; ks < 4; ks++)
            ah[ks] = ok0 ? *(const bf16x8*)(A + (size_t)row0 * 512 + kc * 128 + ks * 32 + kg * 8) : zz;

#pragma unroll
        for (int t = 0; t < 2; t++) {
            const ushort* bh_base = wfh + (size_t)(9 + t * 4 + kc) * 16384;
            const ushort* bl_base = wfl + (size_t)(9 + t * 4 + kc) * 16384;
#pragma unroll
            for (int ks = 0; ks < 4; ks++) {
#pragma unroll
                for (int n = 0; n < 8; n++) {
                    size_t bo = (((size_t)(ks * 8 + n)) * 64 + l) * 8;
                    bf16x8 bh = *(const bf16x8*)(bh_base + bo);
                    bf16x8 bl = *(const bf16x8*)(bl_base + bo);
                    acc[t][n] = __builtin_amdgcn_mfma_f32_16x16x32_bf16(ah[ks], bh, acc[t][n], 0, 0, 0);
                    acc[t][n] = __builtin_amdgcn_mfma_f32_16x16x32_bf16(ah[ks], bl, acc[t][n], 0, 0, 0);
                }
            }
        }
    }

#pragma unroll
    for (int r = 0; r < 4; r++) {
        int row = m0 + kg * 4 + r;
        if (row >= M) continue;
#pragma unroll
        for (int n = 0; n < 8; n++) {
            int col = n * 16 + lr;
            xl2[(size_t)row * 128 + col] = f2bf(acc[0][n][r] + bl2[col]);
            xr2[(size_t)row * 128 + col] = f2bf(acc[1][n][r] + br2[col]);
        }
    }
}

// ---------------- GAT1 edge kernel: anchored softmax, DPP reduce, implicit self-loop ----------------

__global__ __launch_bounds__(256) void gat_edge4(
    const ushort* __restrict__ xlr,   // [N][8][128] bf16
    const float* __restrict__ att,    // [4][128]
    const float* __restrict__ bias,   // [512]
    const int* __restrict__ counts, const int* __restrict__ colA,  // slotted, cap 64
    ushort* __restrict__ h1,          // [N][512] bf16 out (relu'd)
    int N)
{
    int n = blockIdx.x;
    int h = threadIdx.x >> 6, l = threadIdx.x & 63;
    int g = l >> 4, q = l & 15;

    const ushort* xlbase = xlr + h * 128 + q * 8;

    bf16x8 xrv = *(const bf16x8*)(xlr + (size_t)n * 1024 + (4 + h) * 128 + q * 8);
    float4 ata = *(const float4*)(att + h * 128 + q * 8);
    float4 atb = *(const float4*)(att + h * 128 + q * 8 + 4);
    float xr[8], at[8] = {ata.x, ata.y, ata.z, ata.w, atb.x, atb.y, atb.z, atb.w};
#pragma unroll
    for (int j = 0; j < 8; j++) xr[j] = bf2f((ushort)xrv[j]);

    auto dotc = [&](bf16x8 v8, float* vv) -> float {
        float c = 0.f;
#pragma unroll
        for (int j = 0; j < 8; j++) {
            vv[j] = bf2f((ushort)v8[j]);
            float t = vv[j] + xr[j];
            t = fmaxf(t, 0.2f * t);   // leaky relu, 2 VALU ops
            c = fmaf(t, at[j], c);
        }
        return group16_sum(c);
    };

    float selfv[8];
    bf16x8 vself = *(const bf16x8*)(xlbase + (size_t)n * 1024);
    float cs = dotc(vself, selfv);

    int cnt = min(counts[n], 64);
    const int* col = colA + (size_t)n * 64;

    float s = 0.f, o[8];
#pragma unroll
    for (int j = 0; j < 8; j++) o[j] = 0.f;

    auto edge = [&](bf16x8 v8) {
        float vv[8];
        float c = dotc(v8, vv);
        float p = __expf(fminf(c - cs, 80.f));
        s += p;
#pragma unroll
        for (int j = 0; j < 8; j++) o[j] = fmaf(p, vv[j], o[j]);
    };

    for (int base = g; base < cnt; base += 16) {
        int x0 = col[base];
        int x1 = (base + 4  < cnt) ? col[base + 4]  : -1;
        int x2 = (base + 8  < cnt) ? col[base + 8]  : -1;
        int x3 = (base + 12 < cnt) ? col[base + 12] : -1;
        int y1 = (x1 >= 0) ? x1 : n;
        int y2 = (x2 >= 0) ? x2 : n;
        int y3 = (x3 >= 0) ? x3 : n;
        bf16x8 v0 = *(const bf16x8*)(xlbase + (size_t)x0 * 1024);
        bf16x8 v1 = *(const bf16x8*)(xlbase + (size_t)y1 * 1024);
        bf16x8 v2 = *(const bf16x8*)(xlbase + (size_t)y2 * 1024);
        bf16x8 v3 = *(const bf16x8*)(xlbase + (size_t)y3 * 1024);
        edge(v0);
        if (x1 >= 0) edge(v1);
        if (x2 >= 0) edge(v2);
        if (x3 >= 0) edge(v3);
    }

    // merge 4 group partial sums (shared anchor -> plain sums)
#pragma unroll
    for (int off = 16; off <= 32; off <<= 1) {
        s += __shfl_xor(s, off);
#pragma unroll
        for (int j = 0; j < 8; j++) o[j] += __shfl_xor(o[j], off);
    }

    // implicit self-loop: p = exp(cs - cs) = 1
    s += 1.f;
#pragma unroll
    for (int j = 0; j < 8; j++) o[j] += selfv[j];

    if (g == 0) {
        float inv = 1.f / (s + 1e-16f);
        float4 ba = *(const float4*)(bias + h * 128 + q * 8);
        float4 bb = *(const float4*)(bias + h * 128 + q * 8 + 4);
        float bs[8] = {ba.x, ba.y, ba.z, ba.w, bb.x, bb.y, bb.z, bb.w};
        bf16x8 pk;
#pragma unroll
        for (int j = 0; j < 8; j++)
            pk[j] = (short)f2bf(fmaxf(o[j] * inv + bs[j], 0.f));
        *(bf16x8*)(h1 + (size_t)n * 512 + h * 128 + q * 8) = pk;
    }
}

// ---------------- GAT2 edge kernel: 1 head, wave = node, same structure ----------------

__global__ __launch_bounds__(256) void gat_edge1(
    const ushort* __restrict__ xl, const ushort* __restrict__ xr,
    const float* __restrict__ att, const float* __restrict__ bias,
    const int* __restrict__ counts, const int* __restrict__ colA,
    float* __restrict__ out, int N)
{
    int n = blockIdx.x * 4 + (threadIdx.x >> 6);
    if (n >= N) return;
    int l = threadIdx.x & 63;
    int g = l >> 4, q = l & 15;

    const ushort* xlbase = xl + q * 8;

    bf16x8 xrv = *(const bf16x8*)(xr + (size_t)n * 128 + q * 8);
    float4 ata = *(const float4*)(att + q * 8);
    float4 atb = *(const float4*)(att + q * 8 + 4);
    float xrr[8], at[8] = {ata.x, ata.y, ata.z, ata.w, atb.x, atb.y, atb.z, atb.w};
#pragma unroll
    for (int j = 0; j < 8; j++) xrr[j] = bf2f((ushort)xrv[j]);

    auto dotc = [&](bf16x8 v8, float* vv) -> float {
        float c = 0.f;
#pragma unroll
        for (int j = 0; j < 8; j++) {
            vv[j] = bf2f((ushort)v8[j]);
            float t = vv[j] + xrr[j];
            t = fmaxf(t, 0.2f * t);
            c = fmaf(t, at[j], c);
        }
        return group16_sum(c);
    };

    float selfv[8];
    bf16x8 vself = *(const bf16x8*)(xlbase + (size_t)n * 128);
    float cs = dotc(vself, selfv);

    int cnt = min(counts[n], 64);
    const int* col = colA + (size_t)n * 64;

    float s = 0.f, o[8];
#pragma unroll
    for (int j = 0; j < 8; j++) o[j] = 0.f;

    auto edge = [&](bf16x8 v8) {
        float vv[8];
        float c = dotc(v8, vv);
        float p = __expf(fminf(c - cs, 80.f));
        s += p;
#pragma unroll
        for (int j = 0; j < 8; j++) o[j] = fmaf(p, vv[j], o[j]);
    };

    for (int base = g; base < cnt; base += 16) {
        int x0 = col[base];
        int x1 = (base + 4  < cnt) ? col[base + 4]  : -1;
        int x2 = (base + 8  < cnt) ? col[base + 8]  : -1;
        int x3 = (base + 12 < cnt) ? col[base + 12] : -1;
        int y1 = (x1 >= 0) ? x1 : n;
        int y2 = (x2 >= 0) ? x2 : n;
        int y3 = (x3 >= 0) ? x3 : n;
        bf16x8 v0 = *(const bf16x8*)(xlbase + (size_t)x0 * 128);
        bf16x8 v1 = *(const bf16x8*)(xlbase + (size_t)y1 * 128);
        bf16x8 v2 = *(const bf16x8*)(xlbase + (size_t)y2 * 128);
        bf16x8 v3 = *(const bf16x8*)(xlbase + (size_t)y3 * 128);
        edge(v0);
        if (x1 >= 0) edge(v1);
        if (x2 >= 0) edge(v2);
        if (x3 >= 0) edge(v3);
    }

#pragma unroll
    for (int off = 16; off <= 32; off <<= 1) {
        s += __shfl_xor(s, off);
#pragma unroll
        for (int j = 0; j < 8; j++) o[j] += __shfl_xor(o[j], off);
    }

    // implicit self-loop
    s += 1.f;
#pragma unroll
    for (int j = 0; j < 8; j++) o[j] += selfv[j];

    if (g == 0) {
        float inv = 1.f / (s + 1e-16f);
        float4 ba = *(const float4*)(bias + q * 8);
        float4 bb = *(const float4*)(bias + q * 8 + 4);
        float4 r0, r1;
        r0.x = o[0] * inv + ba.x;  r0.y = o[1] * inv + ba.y;
        r0.z = o[2] * inv + ba.z;  r0.w = o[3] * inv + ba.w;
        r1.x = o[4] * inv + bb.x;  r1.y = o[5] * inv + bb.y;
        r1.z = o[6] * inv + bb.z;  r1.w = o[7] * inv + bb.w;
        *(float4*)(out + (size_t)n * 128 + q * 8)     = r0;
        *(float4*)(out + (size_t)n * 128 + q * 8 + 4) = r1;
    }
}

// ---------------- launch ----------------

extern "C" void kernel_launch(void* const* d_in, const int* in_sizes, int n_in,
                              void* d_out, int out_size, void* d_ws, size_t ws_size,
                              hipStream_t stream) {
    const float* x    = (const float*)d_in[0];
    const int* ei     = (const int*)d_in[1];
    const float* W1   = (const float*)d_in[2];
    const float* b1   = (const float*)d_in[3];
    const float* W2   = (const float*)d_in[4];
    const float* b2   = (const float*)d_in[5];
    const float* Wl1  = (const float*)d_in[6];
    const float* bl1  = (const float*)d_in[7];
    const float* Wr1  = (const float*)d_in[8];
    const float* br1  = (const float*)d_in[9];
    const float* att1 = (const float*)d_in[10];
    const float* bias1= (const float*)d_in[11];
    const float* Wl2  = (const float*)d_in[12];
    const float* bl2  = (const float*)d_in[13];
    const float* Wr2  = (const float*)d_in[14];
    const float* br2  = (const float*)d_in[15];
    const float* att2 = (const float*)d_in[16];
    const float* bias2= (const float*)d_in[17];

    int E = in_sizes[1] / 2;
    int N = in_sizes[0] / 5;
    const int* srcE = ei;
    const int* dstE = ei + E;

    float* dout = (float*)d_out;

    // workspace layout (~193 MB)
    ushort* xlr1 = (ushort*)d_ws;                  // N*1024
    ushort* h1   = xlr1 + (size_t)N * 1024;        // N*512
    ushort* h0   = h1 + (size_t)N * 512;           // N*128
    ushort* xr2  = h0 + (size_t)N * 128;           // N*128
    ushort* wfh  = xr2 + (size_t)N * 128;          // 17*16384
    ushort* wfl  = wfh + 17 * 16384;
    int* counts = (int*)(wfl + 17 * 16384);        // N
    int* colA   = counts + N;                      // N*64

    ushort* xl2 = h0;   // h0 dead after gemm_xlr1

    // ---- adjacency (scan-free, slotted) ----
    hipMemsetAsync(counts, 0, (size_t)N * sizeof(int), stream);
    k_fill<<<(E + 255) / 256, 256, 0, stream>>>(srcE, dstE, E, counts, colA);

    // ---- repack ----
    {
        dim3 g(8, 17);
        k_repack<<<g, 256, 0, stream>>>(W2, Wl1, Wr1, Wl2, Wr2, wfh, wfl);
    }

    int mb128 = (N + 127) / 128;
    int mb64  = (N + 63) / 64;

    // ---- fused MLP -> h0 ----
    k_mlp_h0<<<mb128, 256, 0, stream>>>(x, W1, b1, wfh, wfl, b2, h0, N);

    // ---- GAT1 ----
    gemm_xlr1<<<mb128, 256, 0, stream>>>(h0, wfh + 16384, wfl + 16384, bl1, br1, xlr1, N);
    gat_edge4<<<N, 256, 0, stream>>>(xlr1, att1, bias1, counts, colA, h1, N);

    // ---- GAT2 ----
    gemm_xlr2<<<mb64, 256, 0, stream>>>(h1, wfh, wfl, bl2, br2, xl2, xr2, N);
    gat_edge1<<<(N + 3) / 4, 256, 0, stream>>>(xl2, xr2, att2, bias2, counts, colA, dout, N);
}